// Round 24
// baseline (80.925 us; speedup 1.0000x reference)
//
#include <hip/hip_runtime.h>

#define BB 512
#define TT 512
#define KK 128
#define CS 144      // shorts per chain row: 16B-aligned stride (b128-legal)
#define NSEG 32
#define SEGL 16
#define WARM 4      // contraction 0.151^4 ~ 5e-4 nats per junction: negligible

typedef __attribute__((ext_vector_type(8))) short short8;   // 8 x bf16 bits
typedef __attribute__((ext_vector_type(4))) float f32x4;

__device__ __forceinline__ unsigned short f2bf(float f) {
  unsigned u = __float_as_uint(f);
  unsigned r = ((u >> 16) & 1u) + 0x7fffu;
  return (unsigned short)((u + r) >> 16);
}
__device__ __forceinline__ float bf2f(unsigned short h) {
  return __uint_as_float(((unsigned)h) << 16);
}

// K1: 256 blocks x 256 threads = 1024 INDEPENDENT single waves (1 block/CU).
// Wave (bg, s): batches 16bg..16bg+15, segment s of NSEG.
// OPERAND-SWAPPED MFMA (P=16, zero replication):
//   A = E^T tile: A[row=j(16T+row)][k], row = lane&15 -> same fragment data as
//       the old B-fragments (verified loading code).
//   B = state:    B[k][col=chain], col = lane&15 -> 16 DISTINCT chains.
//   D[row][col]: lane (lg,lc) holds chain lc, j = 16T + 4lg + reg (all 4 regs
//       useful). 8 tiles x 4 kc = 32 MFMAs/step advance 16 chain-steps.
// Per step/lane: 4 ds_read_b128 (B), 8 global float4 (pot, 2-phase prefetch),
// 32 exp2+fma+mul, 8 cvt_pk pairs + 8 ds_write_b64. Wave-private LDS double
// buffer -> ZERO barriers, zero cross-wave coupling.
// CONSTANT rescale d=7/step (drift |log2 w| <= ~28 over 20 steps, fp32-safe):
// stored = true * 2^(-7*steps); M deterministic. Junction telescoping (R18-
// verified scheme) via exported (M, state[0]) at warmup-end and segment end.
// __launch_bounds__(256,1): ~270 VGPR (Af=128 + pot=64 + acc=32 + misc) must
// stay in registers; grid=1 block/CU BY DESIGN so the (256,2)-spill /
// (256,1)-occupancy bind of R19/R20 does not apply.
__global__ __launch_bounds__(256, 1) void crf_seg_kernel(
    const float* __restrict__ pot, const int* __restrict__ tags,
    const float* __restrict__ trans, unsigned short* __restrict__ wsv,
    float* __restrict__ wsm, float* __restrict__ wssc) {
  const float C = 1.4426950408889634f;    // 1/ln2
  const int tid = threadIdx.x;
  const int lane = tid & 63;
  const int wv = tid >> 6;
  const int wave_id = blockIdx.x * 4 + wv;
  const int bg = wave_id >> 5;            // batch-group 0..31 (16 batches)
  const int s = wave_id & 31;             // segment 0..31
  const int lg = lane >> 4;               // k-subgroup / j-subrow group
  const int lc = lane & 15;               // chain (B col / D col)

  __shared__ unsigned short sb[4][2][16][CS];  // [wave][parity][chain][j]
  auto* W = sb[wv];

  const int bb = 16 * bg + lc;            // this lane's chain-batch
  const float* pl = pot + (size_t)bb * TT * KK;

  // ---- sequence score (s==0 waves): lane covers batch bb, t in [128lg, +128)
  if (s == 0) {
    float sc = 0.f;
    const int* tg0 = tags + bb * TT;
    const int t0 = 128 * lg;
    for (int tt = 0; tt < 128; tt += 4) {
      int t = t0 + tt;
      int4 tg = *(const int4*)&tg0[t];
      sc += pl[(size_t)(t + 0) * KK + tg.x] + pl[(size_t)(t + 1) * KK + tg.y] +
            pl[(size_t)(t + 2) * KK + tg.z] + pl[(size_t)(t + 3) * KK + tg.w];
      sc += trans[tg.x * KK + tg.y] + trans[tg.y * KK + tg.z] +
            trans[tg.z * KK + tg.w];
      if (t + 4 < TT) sc += trans[tg.w * KK + tg0[t + 4]];
    }
    sc += __shfl_xor(sc, 16, 64);
    sc += __shfl_xor(sc, 32, 64);
    if (lane < 16) wssc[bb] = sc;
  }

  // ---- A fragments (E^T tiles): Af[T][kc][e] = bf16(2^(trans[k][16T+lc]*C)),
  //      k = 32kc + 8lg + e  (identical data to the verified old B-fragments)
  short8 Af[8][4];
  #pragma unroll
  for (int T = 0; T < 8; ++T) {
    #pragma unroll
    for (int kc = 0; kc < 4; ++kc) {
      #pragma unroll
      for (int e = 0; e < 8; ++e)
        Af[T][kc][e] = (short)f2bf(__builtin_amdgcn_exp2f(
            trans[(32 * kc + 8 * lg + e) * KK + 16 * T + lc] * C));
    }
  }

  const int r0 = (s == 0) ? 1 : (SEGL * s - WARM + 1);
  const int nsteps = (s == 0) ? SEGL : ((s == NSEG - 1) ? (WARM + SEGL - 1)
                                                        : (WARM + SEGL));

  // ---- init parity 0: lane fills chain lc, j in [32lg, 32lg+32) ----
  if (s == 0) {
    #pragma unroll
    for (int q = 0; q < 32; ++q) {
      int j = 32 * lg + q;
      W[0][lc][j] = f2bf(__builtin_amdgcn_exp2f(pl[j] * C));   // u_0 (pot row 0)
    }
  } else {
    #pragma unroll
    for (int q = 0; q < 32; ++q) W[0][lc][32 * lg + q] = 0x3F80;  // 1.0
  }

  // ---- pot 2-phase prefetch: 8 float4 per phase at j = 16T + 4lg ----
  float4 pe[8], po[8];
  #pragma unroll
  for (int T = 0; T < 8; ++T) {
    pe[T] = *(const float4*)&pl[(size_t)r0 * KK + 16 * T + 4 * lg];
    po[T] = *(const float4*)&pl[(size_t)(r0 + 1) * KK + 16 * T + 4 * lg];
  }

  int Mi = 0;
  float v00 = 1.f;
  const f32x4 kZ = {0.f, 0.f, 0.f, 0.f};

  auto step = [&](int it, float4 (&cur)[8]) {
    const int p = it & 1, wr = p ^ 1;
    const unsigned short* sp = &W[p][lc][0];
    short8 B0 = *(const short8*)(sp + 8 * lg);        // state[lc][     8lg+e]
    short8 B1 = *(const short8*)(sp + 32 + 8 * lg);   // state[lc][32 + 8lg+e]
    short8 B2 = *(const short8*)(sp + 64 + 8 * lg);
    short8 B3 = *(const short8*)(sp + 96 + 8 * lg);
    int rn = r0 + it + 2;
    if (rn > TT - 1) rn = TT - 1;
    f32x4 acc[8];
    #pragma unroll
    for (int T = 0; T < 8; ++T)
      acc[T] = __builtin_amdgcn_mfma_f32_16x16x32_bf16(Af[T][3], B3, kZ, 0, 0, 0);
    #pragma unroll
    for (int T = 0; T < 8; ++T)
      acc[T] = __builtin_amdgcn_mfma_f32_16x16x32_bf16(Af[T][2], B2, acc[T], 0, 0, 0);
    #pragma unroll
    for (int T = 0; T < 8; ++T)
      acc[T] = __builtin_amdgcn_mfma_f32_16x16x32_bf16(Af[T][1], B1, acc[T], 0, 0, 0);
    #pragma unroll
    for (int T = 0; T < 8; ++T)
      acc[T] = __builtin_amdgcn_mfma_f32_16x16x32_bf16(Af[T][0], B0, acc[T], 0, 0, 0);
    // epilogue: lane owns chain lc, j = 16T + 4lg + (0..3)
    #pragma unroll
    for (int T = 0; T < 8; ++T) {
      float4 u = cur[T];
      cur[T] = *(const float4*)&pl[(size_t)rn * KK + 16 * T + 4 * lg];
      float v0 = acc[T][0] * __builtin_amdgcn_exp2f(fmaf(u.x, C, -7.f));
      float v1 = acc[T][1] * __builtin_amdgcn_exp2f(fmaf(u.y, C, -7.f));
      float v2 = acc[T][2] * __builtin_amdgcn_exp2f(fmaf(u.z, C, -7.f));
      float v3 = acc[T][3] * __builtin_amdgcn_exp2f(fmaf(u.w, C, -7.f));
      if (T == 0) v00 = v0;               // lg==0 lanes: chain lc, j=0
      unsigned w0, w1;
      asm("v_cvt_pk_bf16_f32 %0, %1, %2" : "=v"(w0) : "v"(v0), "v"(v1));
      asm("v_cvt_pk_bf16_f32 %0, %1, %2" : "=v"(w1) : "v"(v2), "v"(v3));
      uint2 pk; pk.x = w0; pk.y = w1;
      *(uint2*)&W[wr][lc][16 * T + 4 * lg] = pk;     // ds_write_b64
    }
    Mi += 7;                              // constant rescale d = 7
  };

  // ---- warmup (s>0): 4 steps, capture "mid" junction ----
  float vMid = 1.f; int MiMid = 0;
  if (s > 0) {
    step(0, pe); step(1, po); step(2, pe); step(3, po);
    vMid = v00; MiMid = Mi;               // state at t = 16s (shifted)
  }
  // ---- main segment ----
  int it = (s > 0) ? WARM : 0;
  for (; it + 1 < nsteps; it += 2) { step(it, pe); step(it + 1, po); }
  if (it < nsteps) step(it, pe);          // s==31 odd tail (it even ✓)

  // ---- export junction scalars: lane<16 (lg==0) owns chain lc = batch bb ----
  if (lane < 16) {
    float* jp = &wsm[((size_t)bb * NSEG + s) * 4];
    jp[0] = (float)MiMid;   // M at warmup end (s>0)
    jp[1] = vMid;           // state[0] at warmup end (s>0)
    jp[2] = (float)Mi;      // M at segment end
    jp[3] = v00;            // state[0] at segment end
  }
  // ---- s==NSEG-1: export final state vectors ----
  if (s == NSEG - 1) {
    const int fin = nsteps & 1;           // 19 -> parity 1
    int c = lane >> 2, j0 = (lane & 3) * 32;
    #pragma unroll
    for (int i = 0; i < 32; i += 8) {
      short8 v = *(const short8*)&W[fin][c][j0 + i];
      *(short8*)&wsv[(size_t)(16 * bg + c) * KK + j0 + i] = v;
    }
  }
}

// K2: per batch: logZ2 = M_end(31) + log2(sum w_31) + telescoped junctions.
__global__ __launch_bounds__(256) void crf_combine_kernel(
    const unsigned short* __restrict__ wsv, const float* __restrict__ wsm,
    const float* __restrict__ wssc, float* __restrict__ out) {
  const float LN2 = 0.6931471805599453f;
  const int tid = threadIdx.x;
  const int lane = tid & 63, wid = tid >> 6;
  const int b = blockIdx.x * 4 + wid;     // 128 blocks x 4 waves = 512
  const unsigned short* vf = wsv + (size_t)b * KK;
  float sum = bf2f(vf[lane]) + bf2f(vf[lane + 64]);
  #pragma unroll
  for (int off = 32; off; off >>= 1) sum += __shfl_xor(sum, off, 64);
  if (lane == 0) {
    auto SC = [&](int s, int k) {
      return wsm[((size_t)b * NSEG + s) * 4 + k];
    };
    float l2 = SC(NSEG - 1, 2) + __builtin_amdgcn_logf(sum);   // v_log = log2
    for (int s = 1; s < NSEG; ++s) {
      l2 += SC(s - 1, 2) + __builtin_amdgcn_logf(SC(s - 1, 3));
      l2 -= SC(s, 0) + __builtin_amdgcn_logf(SC(s, 1));
    }
    out[b] = wssc[b] - l2 * LN2;
  }
}

extern "C" void kernel_launch(void* const* d_in, const int* in_sizes, int n_in,
                              void* d_out, int out_size, void* d_ws, size_t ws_size,
                              hipStream_t stream) {
  const float* pot = (const float*)d_in[0];
  const int* tags = (const int*)d_in[1];
  const float* trans = (const float*)d_in[2];
  float* out = (float*)d_out;
  unsigned short* wsv = (unsigned short*)d_ws;                       // 512x128 bf16
  float* wsm = (float*)((char*)d_ws + (size_t)BB * KK * 2);          // 512x32x4 f32
  float* wssc = (float*)((char*)d_ws + (size_t)BB * KK * 2 +
                         (size_t)BB * NSEG * 4 * 4);                 // 512 f32
  crf_seg_kernel<<<256, 256, 0, stream>>>(pot, tags, trans, wsv, wsm, wssc);
  crf_combine_kernel<<<BB / 4, 256, 0, stream>>>(wsv, wsm, wssc, out);
}